// Round 1
// 239.390 us; speedup vs baseline: 1.0223x; 1.0223x over previous
//
#include <hip/hip_runtime.h>
#include <math.h>

#define Bsz 2
#define Sq  4096
#define Dm  512
#define Hn  8
#define Eh  64

typedef unsigned short u16;
typedef __attribute__((ext_vector_type(8))) short bf16x8;   // 8 bf16 in 4 VGPRs
typedef __attribute__((ext_vector_type(4))) float f32x4;
typedef __attribute__((ext_vector_type(16))) float f32x16;
typedef __attribute__((ext_vector_type(4))) unsigned short u16x4;

// K pre-scale: 1/sqrt(64) * log2(e), folded into k so softmax is a bare exp2.
#define KSCALE 0.18033688011112042f

__device__ __forceinline__ u16 f2bf(float f) {
    unsigned int u = __float_as_uint(f);
    u += 0x7FFFu + ((u >> 16) & 1u);          // round-to-nearest-even
    return (u16)(u >> 16);
}

__device__ __forceinline__ float fast_exp2(float x) {
#if defined(__HIP_DEVICE_COMPILE__) && __has_builtin(__builtin_amdgcn_exp2f)
    return __builtin_amdgcn_exp2f(x);
#else
    return exp2f(x);
#endif
}

// 32x32x16 bf16 MFMA. A: m=lane&31, k=(lane>>5)*8+j. B: n=lane&31, same k.
// D: col=lane&31, row=(r&3)+8*(r>>2)+4*(lane>>5)  [m74/m101-verified].
__device__ __forceinline__ f32x16 mfma_32x32x16(bf16x8 a, bf16x8 b, f32x16 c) {
#if defined(__HIP_DEVICE_COMPILE__)
    return __builtin_amdgcn_mfma_f32_32x32x16_bf16(a, b, c, 0, 0, 0);
#else
    (void)a; (void)b;
    return c;
#endif
}

// v_cvt_pk_bf16_f32: u32 = {hi: bf16(hi), lo: bf16(lo)}  (no builtin on gfx950)
__device__ __forceinline__ unsigned cvt_pk_bf16(float lo, float hi) {
#if defined(__HIP_DEVICE_COMPILE__)
    unsigned r;
    asm("v_cvt_pk_bf16_f32 %0, %1, %2" : "=v"(r) : "v"(lo), "v"(hi));
    return r;
#else
    return ((unsigned)f2bf(hi) << 16) | (unsigned)f2bf(lo);
#endif
}

// v_permlane32_swap_b32: a' = [a.lanes0-31, b.lanes0-31], b' = [a.lanes32-63, b.lanes32-63]
__device__ __forceinline__ void plane32_swap(unsigned &a, unsigned &b) {
#if defined(__HIP_DEVICE_COMPILE__)
    asm volatile("v_permlane32_swap_b32 %0, %1" : "+v"(a), "+v"(b));
#endif
}

__device__ __forceinline__ bf16x8 frag_of(unsigned a, unsigned b, unsigned c, unsigned d) {
    union { unsigned u[4]; bf16x8 v; } r;
    r.u[0] = a; r.u[1] = b; r.u[2] = c; r.u[3] = d;
    return r.v;
}

// async global->LDS, 16B per lane. LDS dest = wave-uniform base + lane*16.
__device__ __forceinline__ void async16(const u16* g, u16* l) {
    __builtin_amdgcn_global_load_lds(
        (const __attribute__((address_space(1))) void*)g,
        (__attribute__((address_space(3))) void*)l, 16, 0, 0);
}

// ---------------------------------------------------------------------------
// bf16 MFMA GEMM core (r10 single-buffered version).
// C[128 x TN] += A[128,512] * WT[TN,512]^T, K=Dm=512.
// Global-side XOR chunk swizzle; 4 waves as 2(M)x2(N).
// ---------------------------------------------------------------------------
template<int TN, int NT>
__device__ __forceinline__ void gemm_core(
    const u16* __restrict__ A, const u16* __restrict__ WT,
    int m0, int n0, u16* Ast, u16* Bst, f32x4 (&acc)[4][NT])
{
    const int tid  = threadIdx.x;
    const int lane = tid & 63, wid = tid >> 6;
    const int l15  = lane & 15, quad = lane >> 4;
    const int wm = wid >> 1, wn = wid & 1;

    for (int kt = 0; kt < Dm / 64; ++kt) {
        const int k0 = kt * 64;
        __syncthreads();
#pragma unroll
        for (int j = 0; j < 4; ++j) {
            int ci = wid * 256 + j * 64 + lane;
            int row = ci >> 3, c = (ci & 7) ^ (row & 7);
            async16(&A[(size_t)(m0 + row) * Dm + k0 + c * 8],
                    &Ast[(size_t)(wid * 256 + j * 64) * 8]);
        }
#pragma unroll
        for (int j = 0; j < TN / 32; ++j) {
            int ci = wid * (TN * 2) + j * 64 + lane;
            int row = ci >> 3, c = (ci & 7) ^ (row & 7);
            async16(&WT[(size_t)(n0 + row) * Dm + k0 + c * 8],
                    &Bst[(size_t)(wid * (TN * 2) + j * 64) * 8]);
        }
        __syncthreads();
#pragma unroll
        for (int ks = 0; ks < 2; ++ks) {
            bf16x8 af[4], bfr[NT];
#pragma unroll
            for (int mt = 0; mt < 4; ++mt) {
                int r = wm * 64 + mt * 16 + l15;
                af[mt] = *(const bf16x8*)&Ast[(r * 8 + ((ks * 4 + quad) ^ (r & 7))) * 8];
            }
#pragma unroll
            for (int nt = 0; nt < NT; ++nt) {
                int n = wn * (TN / 2) + nt * 16 + l15;
                bfr[nt] = *(const bf16x8*)&Bst[(n * 8 + ((ks * 4 + quad) ^ (n & 7))) * 8];
            }
#pragma unroll
            for (int mt = 0; mt < 4; ++mt)
#pragma unroll
                for (int nt = 0; nt < NT; ++nt)
                    acc[mt][nt] = __builtin_amdgcn_mfma_f32_16x16x32_bf16(
                        af[mt], bfr[nt], acc[mt][nt], 0, 0, 0);
        }
    }
}

// ---------------------------------------------------------------------------
// prep: seg0 x->bf16; seg1-3 wq/wk/wv transpose; seg4-6 wo/w1/w2 transpose;
// seg7 bo reduce.
// ---------------------------------------------------------------------------
__global__ __launch_bounds__(256) void prep_kernel(
    const float* __restrict__ x,
    const float* __restrict__ wq, const float* __restrict__ wk,
    const float* __restrict__ wv, const float* __restrict__ wo,
    const float* __restrict__ w1, const float* __restrict__ w2,
    const float* __restrict__ bo,
    u16* __restrict__ xb, u16* __restrict__ wqkvT, u16* __restrict__ woT,
    u16* __restrict__ w1T, u16* __restrict__ w2T, float* __restrict__ bo_s)
{
    const int seg = blockIdx.y, bx = blockIdx.x, tid = threadIdx.x;
    if (seg == 0) {
        const float4* xi = (const float4*)x;
        for (int i = bx * 256 + tid; i < (Bsz * Sq * Dm) / 4; i += 64 * 256) {
            float4 v = xi[i];
            u16x4 o = {f2bf(v.x), f2bf(v.y), f2bf(v.z), f2bf(v.w)};
            *(u16x4*)&xb[(size_t)i * 4] = o;
        }
        return;
    }
    if (seg == 7) {
        int d = bx * 256 + tid;
        if (d < Dm) {
            float s = 0.0f;
#pragma unroll
            for (int h = 0; h < Hn; ++h) s += bo[h * Dm + d];
            bo_s[d] = s;
        }
        return;
    }
    __shared__ float t[64][65];
    const float* src; u16* dst; int ld_in;
    if (seg <= 3) {
        const float* w = (seg == 1) ? wq : (seg == 2) ? wk : wv;
        int head = bx >> 3, kt = bx & 7;
        src = w + (size_t)head * Dm * Eh + (size_t)kt * 64 * 64;
        ld_in = 64;
        dst = wqkvT + ((size_t)((seg - 1) * 8 + head) * 64) * 512 + kt * 64;
    } else {
        const float* w = (seg == 4) ? wo : (seg == 5) ? w1 : w2;
        u16* dT = (seg == 4) ? woT : (seg == 5) ? w1T : w2T;
        int tr = bx >> 3, tc = bx & 7;
        src = w + (size_t)(tr * 64) * 512 + tc * 64;
        ld_in = 512;
        dst = dT + (size_t)(tc * 64) * 512 + tr * 64;
    }
#pragma unroll
    for (int it = 0; it < 16; ++it) {
        int idx = it * 256 + tid;
        int r = idx >> 6, c = idx & 63;
        t[r][c] = src[(size_t)r * ld_in + c];
    }
    __syncthreads();
#pragma unroll
    for (int it = 0; it < 4; ++it) {
        int idx = it * 256 + tid;
        int oc = idx >> 4, og = idx & 15;
        u16x4 o;
#pragma unroll
        for (int j = 0; j < 4; ++j) o[j] = f2bf(t[og * 4 + j][oc]);
        *(u16x4*)&dst[(size_t)oc * 512 + og * 4] = o;
    }
}

// ---------------------------------------------------------------------------
// QKV: grid (64, 24). Tile 128x64. q -> [bh][s][e]; k -> [bh][s][e] scaled
// by KSCALE (folded softmax scale + log2e); v -> transposed [bh][e][s].
// ---------------------------------------------------------------------------
__global__ __launch_bounds__(256, 2) void qkv_gemm(
    const u16* __restrict__ xb, const u16* __restrict__ wqkvT,
    const float* __restrict__ bq, const float* __restrict__ bk,
    const float* __restrict__ bv,
    u16* __restrict__ qb, u16* __restrict__ kb, u16* __restrict__ vbT)
{
    __shared__ __align__(16) u16 Ast[128 * 64];
    __shared__ __align__(16) u16 Bst[64 * 64];
    const int proj = blockIdx.y >> 3, h = blockIdx.y & 7;
    const u16* WT = wqkvT + (size_t)blockIdx.y * 64 * 512;

    f32x4 acc[4][2];
#pragma unroll
    for (int i = 0; i < 4; ++i)
#pragma unroll
        for (int j = 0; j < 2; ++j) acc[i][j] = (f32x4)0.0f;

    gemm_core<64, 2>(xb, WT, blockIdx.x * 128, 0, Ast, Bst, acc);

    const int tid = threadIdx.x;
    const int lane = tid & 63, wid = tid >> 6;
    const int l15 = lane & 15, quad = lane >> 4;
    const int wm = wid >> 1, wn = wid & 1;
    const float* bias = (proj == 0) ? bq : (proj == 1) ? bk : bv;

    const int mbase = blockIdx.x * 128 + wm * 64;
    const int b = mbase >> 12;
    const int sbase = (mbase & (Sq - 1));
    const int bh = b * Hn + h;

#pragma unroll
    for (int mt = 0; mt < 4; ++mt)
#pragma unroll
        for (int nt = 0; nt < 2; ++nt) {
            int e = wn * 32 + nt * 16 + l15;
            float bval = bias[h * Eh + e];
            int s = sbase + mt * 16 + quad * 4;
            if (proj == 2) {
                u16x4 o;
#pragma unroll
                for (int r = 0; r < 4; ++r) o[r] = f2bf(acc[mt][nt][r] + bval);
                *(u16x4*)&vbT[((size_t)bh * Eh + e) * Sq + s] = o;
            } else if (proj == 1) {
                for (int r = 0; r < 4; ++r)
                    kb[((size_t)bh * Sq + s + r) * Eh + e] =
                        f2bf((acc[mt][nt][r] + bval) * KSCALE);
            } else {
                for (int r = 0; r < 4; ++r)
                    qb[((size_t)bh * Sq + s + r) * Eh + e] = f2bf(acc[mt][nt][r] + bval);
            }
        }
}

// ---------------------------------------------------------------------------
// bf16 MFMA flash attention v13 = v12 staging/tiling + full 32x32x16 MFMA.
// PV was on 16x16x16 (half FLOP-rate: same pipe cycles as x32 for half the
// MACs) -> 42% of the kernel was matrix-pipe occupancy. Now:
//   S^T(32t x 32q) = K'*Q^T via 32x32x16 (4 ks steps), D row=t, col=q.
//   P fragments for PV built in-register: 8x v_cvt_pk_bf16_f32 (pair regs
//   2j,2j+1) + 4x v_permlane32_swap_b32 per 32-t tile (T12 recipe):
//     swap(x0,x2),swap(x1,x3) -> frag0 regs {0,2},{1,3} in place (t 0-15)
//     swap(x4,x6),swap(x5,x7) -> frag1 (t 16-31)
//   O^T(64e x 32q) += V^T * P^T via 32x32x16, 2 e-tiles.
// MFMA instrs/wave-iter: 96 (x16-mixed) -> 32 (all x32-class full rate).
// Per-wave q = 32 (wid*32), all 128 t per iter; LDS layouts unchanged.
// ---------------------------------------------------------------------------
__global__ __launch_bounds__(256, 2) void attn_kernel(
    const u16* __restrict__ qb, const u16* __restrict__ kb,
    const u16* __restrict__ vbT, u16* __restrict__ ctxb)
{
    __shared__ __align__(16) u16 kst[2][128 * 64];  // [t][d] chunks, swizzled
    __shared__ __align__(16) u16 vst[2][64 * 128];  // [e][t] chunks, swizzled

    const int tid  = threadIdx.x;
    const int lane = tid & 63, wid = tid >> 6;
    const int l31  = lane & 31, hh = lane >> 5;
    const int bh = blockIdx.y;
    const int q0 = blockIdx.x * 128;
    const int b = bh >> 3, h = bh & 7;

    const u16* qg = qb + (size_t)bh * Sq * Eh;
    const u16* kg = kb + (size_t)bh * Sq * Eh;
    const u16* vg = vbT + (size_t)bh * Eh * Sq;

    // staging geometry: 1024 chunks per tensor, 4 async16/wave/tensor.
    // K tile [t 0..127][d 0..63]: row=ci>>3, col=ci&7, XOR row&7.
    // V tile [e 0..63][t 0..127]: row=ci>>4, col=ci&15, XOR low-3 bits.
    int krow[4], kcol[4], vrow[4], vcol[4];
#pragma unroll
    for (int j = 0; j < 4; ++j) {
        int ci = wid * 256 + j * 64 + lane;
        krow[j] = ci >> 3;
        kcol[j] = (ci & 7) ^ (krow[j] & 7);
        vrow[j] = ci >> 4;
        int vc  = ci & 15;
        vcol[j] = (vc & 8) | ((vc & 7) ^ (vrow[j] & 7));
    }

    // Q B-frags (n=q=lane&31, k=d=ks*16+hh*8+j) in registers for the kernel
    bf16x8 qf[4];
    {
        const u16* qrow = &qg[(size_t)(q0 + wid * 32 + l31) * Eh + hh * 8];
#pragma unroll
        for (int ks = 0; ks < 4; ++ks)
            qf[ks] = *(const bf16x8*)&qrow[ks * 16];
    }

    f32x16 O[2];                 // O^T[e-tile], D rows = e_local
    O[0] = (f32x16)0.0f;
    O[1] = (f32x16)0.0f;
    float lp = 0.0f;

    // issue tile 0 into buffer 0
#pragma unroll
    for (int j = 0; j < 4; ++j) {
        async16(&kg[(size_t)krow[j] * Eh + kcol[j] * 8],
                &kst[0][(wid * 256 + j * 64) * 8]);
        async16(&vg[(size_t)vrow[j] * Sq + vcol[j] * 8],
                &vst[0][(wid * 256 + j * 64) * 8]);
    }

    const int t7 = l31 & 7;      // (tt*32+l31)&7 == (et*32+l31)&7

    for (int kt = 0; kt < Sq / 128; ++kt) {
        const int cur = kt & 1;
        __syncthreads();   // drains tile kt's async loads; frees other buffer

        if (kt < Sq / 128 - 1) {
            const int t1 = (kt + 1) * 128;
#pragma unroll
            for (int j = 0; j < 4; ++j) {
                async16(&kg[(size_t)(t1 + krow[j]) * Eh + kcol[j] * 8],
                        &kst[cur ^ 1][(wid * 256 + j * 64) * 8]);
                async16(&vg[(size_t)vrow[j] * Sq + t1 + vcol[j] * 8],
                        &vst[cur ^ 1][(wid * 256 + j * 64) * 8]);
            }
        }

        const u16* kcur = kst[cur];
        const u16* vcur = vst[cur];

#pragma unroll
        for (int tt = 0; tt < 4; ++tt) {
            // ---- S^T(32t x 32q) = K' Q^T, 4x 32x32x16 over d ----
            f32x16 S = (f32x16)0.0f;
            const int trow = (tt * 32 + l31) * 64;
#pragma unroll
            for (int ks = 0; ks < 4; ++ks) {
                bf16x8 kf = *(const bf16x8*)&kcur[trow + ((ks * 2 + hh) ^ t7) * 8];
                S = mfma_32x32x16(kf, qf[ks], S);
            }

            // ---- exp2 + pack pairs + permlane32_swap -> PV B-frags ----
            // x_j = pack(S[2j],S[2j+1]); t(reg r) = (r&3)+8*(r>>2)+4*hh.
            unsigned px[8];
#pragma unroll
            for (int j = 0; j < 8; ++j) {
                float p0 = fast_exp2(S[2 * j]);
                float p1 = fast_exp2(S[2 * j + 1]);
                lp += p0 + p1;
                px[j] = cvt_pk_bf16(p0, p1);
            }
            plane32_swap(px[0], px[2]);
            plane32_swap(px[1], px[3]);
            plane32_swap(px[4], px[6]);
            plane32_swap(px[5], px[7]);
            bf16x8 f0 = frag_of(px[0], px[1], px[2], px[3]);  // t 0..15 of tile
            bf16x8 f1 = frag_of(px[4], px[5], px[6], px[7]);  // t 16..31

            // ---- O^T += V^T P^T (A = V^T: m=e, k=t) ----
#pragma unroll
            for (int et = 0; et < 2; ++et) {
                const int erow = (et * 32 + l31) * 128;
                int c0 = tt * 4 + hh;         // 16B chunk for kb = 2tt
                int c1 = c0 + 2;              // kb = 2tt+1
                int g0 = (c0 & 8) | ((c0 & 7) ^ t7);
                int g1 = (c1 & 8) | ((c1 & 7) ^ t7);
                bf16x8 v0 = *(const bf16x8*)&vcur[erow + g0 * 8];
                bf16x8 v1 = *(const bf16x8*)&vcur[erow + g1 * 8];
                O[et] = mfma_32x32x16(v0, f0, O[et]);
                O[et] = mfma_32x32x16(v1, f1, O[et]);
            }
        }
    }

    // ---- l: lane half hh holds t residues {0-3,8-11,..}+4hh; partner is ^32
    lp += __shfl_xor(lp, 32, 64);
    const float rl = 1.0f / lp;

    // ---- normalize (per-lane q = l31) and store u16x4 along e ----
    const int qglob = q0 + wid * 32 + l31;
    u16* crow = ctxb + ((size_t)(b * Sq + qglob) * Hn + h) * Eh;
#pragma unroll
    for (int et = 0; et < 2; ++et)
#pragma unroll
        for (int g = 0; g < 4; ++g) {
            u16x4 o;
#pragma unroll
            for (int i = 0; i < 4; ++i) o[i] = f2bf(O[et][g * 4 + i] * rl);
            *(u16x4*)&crow[et * 32 + g * 8 + hh * 4] = o;
        }
}

// ---------------------------------------------------------------------------
// Flat GEMM [8192,512] x WT[512,512], tile 128x64 (512 blocks, 2/CU).
// MODE 0: bf16 out; 1: bf16 out + relu; 2: fp32 out.
// ---------------------------------------------------------------------------
template<int MODE>
__global__ __launch_bounds__(256, 2) void gemmMN(
    const u16* __restrict__ A, const u16* __restrict__ WT,
    const float* __restrict__ bias, void* __restrict__ Cout)
{
    __shared__ __align__(16) u16 Ast[128 * 64];
    __shared__ __align__(16) u16 Bst[64 * 64];

    f32x4 acc[4][2];
#pragma unroll
    for (int i = 0; i < 4; ++i)
#pragma unroll
        for (int j = 0; j < 2; ++j) acc[i][j] = (f32x4)0.0f;

    gemm_core<64, 2>(A, WT, blockIdx.x * 128, blockIdx.y * 64, Ast, Bst, acc);

    const int tid = threadIdx.x;
    const int lane = tid & 63, wid = tid >> 6;
    const int l15 = lane & 15, quad = lane >> 4;
    const int m0 = blockIdx.x * 128 + (wid >> 1) * 64;
    const int n0 = blockIdx.y * 64 + (wid & 1) * 32;

#pragma unroll
    for (int mt = 0; mt < 4; ++mt)
#pragma unroll
        for (int nt = 0; nt < 2; ++nt) {
            int col = n0 + nt * 16 + l15;
            float bval = bias[col];
#pragma unroll
            for (int r = 0; r < 4; ++r) {
                int row = m0 + mt * 16 + quad * 4 + r;
                float v = acc[mt][nt][r] + bval;
                if (MODE == 1) v = fmaxf(v, 0.0f);
                if (MODE == 2) ((float*)Cout)[(size_t)row * Dm + col] = v;
                else           ((u16*)Cout)[(size_t)row * Dm + col] = f2bf(v);
            }
        }
}

extern "C" void kernel_launch(void* const* d_in, const int* in_sizes, int n_in,
                              void* d_out, int out_size, void* d_ws, size_t ws_size,
                              hipStream_t stream)
{
    const float* x  = (const float*)d_in[0];
    const float* wq = (const float*)d_in[1];
    const float* bq = (const float*)d_in[2];
    const float* wk = (const float*)d_in[3];
    const float* bk = (const float*)d_in[4];
    const float* wv = (const float*)d_in[5];
    const float* bv = (const float*)d_in[6];
    const float* wo = (const float*)d_in[7];
    const float* bo = (const float*)d_in[8];
    const float* w1 = (const float*)d_in[9];
    const float* b1 = (const float*)d_in[10];
    const float* w2 = (const float*)d_in[11];
    const float* b2 = (const float*)d_in[12];
    float* out = (float*)d_out;
    char* wsb = (char*)d_ws;

    const size_t MB = 1u << 20;
    u16*   xb    = (u16*)(wsb + 0);        // 8 MB  bf16 [B*S, D]
    u16*   qb    = (u16*)(wsb + 8 * MB);   // 8 MB  [bh][s][e]
    u16*   kb    = (u16*)(wsb + 16 * MB);  // 8 MB  [bh][s][e] (pre-scaled)
    u16*   vbT   = (u16*)(wsb + 24 * MB);  // 8 MB  [bh][e][s]
    u16*   ctxb  = (u16*)(wsb + 32 * MB);  // 8 MB  [b][s][h][e]
    u16*   ybuf  = (u16*)(wsb + 40 * MB);  // 8 MB
    u16*   h1    = (u16*)(wsb + 48 * MB);  // 8 MB
    u16*   wqkvT = (u16*)(wsb + 56 * MB);  // 1.5 MB
    u16*   woT   = (u16*)(wsb + 58 * MB);  // 0.5 MB
    u16*   w1T   = (u16*)(wsb + 59 * MB);  // 0.5 MB
    u16*   w2T   = (u16*)(wsb + 60 * MB);  // 0.5 MB
    float* bo_s  = (float*)(wsb + 61 * MB);

    prep_kernel<<<dim3(64, 8), 256, 0, stream>>>(
        x, wq, wk, wv, wo, w1, w2, bo, xb, wqkvT, woT, w1T, w2T, bo_s);
    qkv_gemm<<<dim3(Sq * Bsz / 128, 24), 256, 0, stream>>>(
        xb, wqkvT, bq, bk, bv, qb, kb, vbT);
    attn_kernel<<<dim3(Sq / 128, Bsz * Hn), 256, 0, stream>>>(qb, kb, vbT, ctxb);
    gemmMN<0><<<dim3(Bsz * Sq / 128, Dm / 64), 256, 0, stream>>>(ctxb, woT, bo_s, ybuf);
    gemmMN<1><<<dim3(Bsz * Sq / 128, Dm / 64), 256, 0, stream>>>(ybuf, w1T, b1, h1);
    gemmMN<2><<<dim3(Bsz * Sq / 128, Dm / 64), 256, 0, stream>>>(h1, w2T, b2, out);
}

// Round 2
// 236.054 us; speedup vs baseline: 1.0367x; 1.0141x over previous
//
#include <hip/hip_runtime.h>
#include <math.h>

#define Bsz 2
#define Sq  4096
#define Dm  512
#define Hn  8
#define Eh  64

typedef unsigned short u16;
typedef __attribute__((ext_vector_type(8))) short bf16x8;   // 8 bf16 in 4 VGPRs
typedef __attribute__((ext_vector_type(4))) float f32x4;
typedef __attribute__((ext_vector_type(16))) float f32x16;
typedef __attribute__((ext_vector_type(4))) unsigned short u16x4;

// K pre-scale: 1/sqrt(64) * log2(e), folded into k so softmax is a bare exp2.
#define KSCALE 0.18033688011112042f

__device__ __forceinline__ u16 f2bf(float f) {
    unsigned int u = __float_as_uint(f);
    u += 0x7FFFu + ((u >> 16) & 1u);          // round-to-nearest-even
    return (u16)(u >> 16);
}

__device__ __forceinline__ float fast_exp2(float x) {
#if defined(__HIP_DEVICE_COMPILE__) && __has_builtin(__builtin_amdgcn_exp2f)
    return __builtin_amdgcn_exp2f(x);
#else
    return exp2f(x);
#endif
}

// 32x32x16 bf16 MFMA. A: m=lane&31, k=(lane>>5)*8+j. B: n=lane&31, same k.
// D: col=lane&31, row=(r&3)+8*(r>>2)+4*(lane>>5)  [m74/m101-verified].
__device__ __forceinline__ f32x16 mfma_32x32x16(bf16x8 a, bf16x8 b, f32x16 c) {
#if defined(__HIP_DEVICE_COMPILE__)
    return __builtin_amdgcn_mfma_f32_32x32x16_bf16(a, b, c, 0, 0, 0);
#else
    (void)a; (void)b;
    return c;
#endif
}

// v_cvt_pk_bf16_f32: u32 = {hi: bf16(hi), lo: bf16(lo)}  (no builtin on gfx950)
__device__ __forceinline__ unsigned cvt_pk_bf16(float lo, float hi) {
#if defined(__HIP_DEVICE_COMPILE__)
    unsigned r;
    asm("v_cvt_pk_bf16_f32 %0, %1, %2" : "=v"(r) : "v"(lo), "v"(hi));
    return r;
#else
    return ((unsigned)f2bf(hi) << 16) | (unsigned)f2bf(lo);
#endif
}

// v_permlane32_swap_b32: a' = [a.lanes0-31, b.lanes0-31], b' = [a.lanes32-63, b.lanes32-63]
__device__ __forceinline__ void plane32_swap(unsigned &a, unsigned &b) {
#if defined(__HIP_DEVICE_COMPILE__)
    asm volatile("v_permlane32_swap_b32 %0, %1" : "+v"(a), "+v"(b));
#endif
}

__device__ __forceinline__ bf16x8 frag_of(unsigned a, unsigned b, unsigned c, unsigned d) {
    union { unsigned u[4]; bf16x8 v; } r;
    r.u[0] = a; r.u[1] = b; r.u[2] = c; r.u[3] = d;
    return r.v;
}

// async global->LDS, 16B per lane. LDS dest = wave-uniform base + lane*16.
__device__ __forceinline__ void async16(const u16* g, u16* l) {
    __builtin_amdgcn_global_load_lds(
        (const __attribute__((address_space(1))) void*)g,
        (__attribute__((address_space(3))) void*)l, 16, 0, 0);
}

// ---------------------------------------------------------------------------
// bf16 MFMA GEMM core (r10 single-buffered version).
// C[128 x TN] += A[128,512] * WT[TN,512]^T, K=Dm=512.
// Global-side XOR chunk swizzle; 4 waves as 2(M)x2(N).
// ---------------------------------------------------------------------------
template<int TN, int NT>
__device__ __forceinline__ void gemm_core(
    const u16* __restrict__ A, const u16* __restrict__ WT,
    int m0, int n0, u16* Ast, u16* Bst, f32x4 (&acc)[4][NT])
{
    const int tid  = threadIdx.x;
    const int lane = tid & 63, wid = tid >> 6;
    const int l15  = lane & 15, quad = lane >> 4;
    const int wm = wid >> 1, wn = wid & 1;

    for (int kt = 0; kt < Dm / 64; ++kt) {
        const int k0 = kt * 64;
        __syncthreads();
#pragma unroll
        for (int j = 0; j < 4; ++j) {
            int ci = wid * 256 + j * 64 + lane;
            int row = ci >> 3, c = (ci & 7) ^ (row & 7);
            async16(&A[(size_t)(m0 + row) * Dm + k0 + c * 8],
                    &Ast[(size_t)(wid * 256 + j * 64) * 8]);
        }
#pragma unroll
        for (int j = 0; j < TN / 32; ++j) {
            int ci = wid * (TN * 2) + j * 64 + lane;
            int row = ci >> 3, c = (ci & 7) ^ (row & 7);
            async16(&WT[(size_t)(n0 + row) * Dm + k0 + c * 8],
                    &Bst[(size_t)(wid * (TN * 2) + j * 64) * 8]);
        }
        __syncthreads();
#pragma unroll
        for (int ks = 0; ks < 2; ++ks) {
            bf16x8 af[4], bfr[NT];
#pragma unroll
            for (int mt = 0; mt < 4; ++mt) {
                int r = wm * 64 + mt * 16 + l15;
                af[mt] = *(const bf16x8*)&Ast[(r * 8 + ((ks * 4 + quad) ^ (r & 7))) * 8];
            }
#pragma unroll
            for (int nt = 0; nt < NT; ++nt) {
                int n = wn * (TN / 2) + nt * 16 + l15;
                bfr[nt] = *(const bf16x8*)&Bst[(n * 8 + ((ks * 4 + quad) ^ (n & 7))) * 8];
            }
#pragma unroll
            for (int mt = 0; mt < 4; ++mt)
#pragma unroll
                for (int nt = 0; nt < NT; ++nt)
                    acc[mt][nt] = __builtin_amdgcn_mfma_f32_16x16x32_bf16(
                        af[mt], bfr[nt], acc[mt][nt], 0, 0, 0);
        }
    }
}

// ---------------------------------------------------------------------------
// prep: seg0 x->bf16; seg1-3 wq/wk/wv transpose; seg4-6 wo/w1/w2 transpose;
// seg7 bo reduce.
// ---------------------------------------------------------------------------
__global__ __launch_bounds__(256) void prep_kernel(
    const float* __restrict__ x,
    const float* __restrict__ wq, const float* __restrict__ wk,
    const float* __restrict__ wv, const float* __restrict__ wo,
    const float* __restrict__ w1, const float* __restrict__ w2,
    const float* __restrict__ bo,
    u16* __restrict__ xb, u16* __restrict__ wqkvT, u16* __restrict__ woT,
    u16* __restrict__ w1T, u16* __restrict__ w2T, float* __restrict__ bo_s)
{
    const int seg = blockIdx.y, bx = blockIdx.x, tid = threadIdx.x;
    if (seg == 0) {
        const float4* xi = (const float4*)x;
        for (int i = bx * 256 + tid; i < (Bsz * Sq * Dm) / 4; i += 64 * 256) {
            float4 v = xi[i];
            u16x4 o = {f2bf(v.x), f2bf(v.y), f2bf(v.z), f2bf(v.w)};
            *(u16x4*)&xb[(size_t)i * 4] = o;
        }
        return;
    }
    if (seg == 7) {
        int d = bx * 256 + tid;
        if (d < Dm) {
            float s = 0.0f;
#pragma unroll
            for (int h = 0; h < Hn; ++h) s += bo[h * Dm + d];
            bo_s[d] = s;
        }
        return;
    }
    __shared__ float t[64][65];
    const float* src; u16* dst; int ld_in;
    if (seg <= 3) {
        const float* w = (seg == 1) ? wq : (seg == 2) ? wk : wv;
        int head = bx >> 3, kt = bx & 7;
        src = w + (size_t)head * Dm * Eh + (size_t)kt * 64 * 64;
        ld_in = 64;
        dst = wqkvT + ((size_t)((seg - 1) * 8 + head) * 64) * 512 + kt * 64;
    } else {
        const float* w = (seg == 4) ? wo : (seg == 5) ? w1 : w2;
        u16* dT = (seg == 4) ? woT : (seg == 5) ? w1T : w2T;
        int tr = bx >> 3, tc = bx & 7;
        src = w + (size_t)(tr * 64) * 512 + tc * 64;
        ld_in = 512;
        dst = dT + (size_t)(tc * 64) * 512 + tr * 64;
    }
#pragma unroll
    for (int it = 0; it < 16; ++it) {
        int idx = it * 256 + tid;
        int r = idx >> 6, c = idx & 63;
        t[r][c] = src[(size_t)r * ld_in + c];
    }
    __syncthreads();
#pragma unroll
    for (int it = 0; it < 4; ++it) {
        int idx = it * 256 + tid;
        int oc = idx >> 4, og = idx & 15;
        u16x4 o;
#pragma unroll
        for (int j = 0; j < 4; ++j) o[j] = f2bf(t[og * 4 + j][oc]);
        *(u16x4*)&dst[(size_t)oc * 512 + og * 4] = o;
    }
}

// ---------------------------------------------------------------------------
// QKV: grid (64, 24). Tile 128x64. q -> [bh][s][e]; k -> [bh][s][e] scaled
// by KSCALE (folded softmax scale + log2e); v -> transposed [bh][e][s].
// ---------------------------------------------------------------------------
__global__ __launch_bounds__(256, 2) void qkv_gemm(
    const u16* __restrict__ xb, const u16* __restrict__ wqkvT,
    const float* __restrict__ bq, const float* __restrict__ bk,
    const float* __restrict__ bv,
    u16* __restrict__ qb, u16* __restrict__ kb, u16* __restrict__ vbT)
{
    __shared__ __align__(16) u16 Ast[128 * 64];
    __shared__ __align__(16) u16 Bst[64 * 64];
    const int proj = blockIdx.y >> 3, h = blockIdx.y & 7;
    const u16* WT = wqkvT + (size_t)blockIdx.y * 64 * 512;

    f32x4 acc[4][2];
#pragma unroll
    for (int i = 0; i < 4; ++i)
#pragma unroll
        for (int j = 0; j < 2; ++j) acc[i][j] = (f32x4)0.0f;

    gemm_core<64, 2>(xb, WT, blockIdx.x * 128, 0, Ast, Bst, acc);

    const int tid = threadIdx.x;
    const int lane = tid & 63, wid = tid >> 6;
    const int l15 = lane & 15, quad = lane >> 4;
    const int wm = wid >> 1, wn = wid & 1;
    const float* bias = (proj == 0) ? bq : (proj == 1) ? bk : bv;

    const int mbase = blockIdx.x * 128 + wm * 64;
    const int b = mbase >> 12;
    const int sbase = (mbase & (Sq - 1));
    const int bh = b * Hn + h;

#pragma unroll
    for (int mt = 0; mt < 4; ++mt)
#pragma unroll
        for (int nt = 0; nt < 2; ++nt) {
            int e = wn * 32 + nt * 16 + l15;
            float bval = bias[h * Eh + e];
            int s = sbase + mt * 16 + quad * 4;
            if (proj == 2) {
                u16x4 o;
#pragma unroll
                for (int r = 0; r < 4; ++r) o[r] = f2bf(acc[mt][nt][r] + bval);
                *(u16x4*)&vbT[((size_t)bh * Eh + e) * Sq + s] = o;
            } else if (proj == 1) {
                for (int r = 0; r < 4; ++r)
                    kb[((size_t)bh * Sq + s + r) * Eh + e] =
                        f2bf((acc[mt][nt][r] + bval) * KSCALE);
            } else {
                for (int r = 0; r < 4; ++r)
                    qb[((size_t)bh * Sq + s + r) * Eh + e] = f2bf(acc[mt][nt][r] + bval);
            }
        }
}

// ---------------------------------------------------------------------------
// bf16 MFMA flash attention v14 = v13 math + 8-wave t-split occupancy fix.
// v13 post-mortem: MFMA pipe halved (MfmaUtil 45->29.5) but wall flat ->
// binding resource was VALU-issue + idle at 2 waves/SIMD (grid 512 x 64KB
// LDS = 2 blocks/CU = 8 waves/CU). Now 512-thread blocks: 4 q-waves x
// 2 t-halves; same tiles, same LDS, same grid -> 16 waves/CU = 4/SIMD.
// Per wave: q=32 rows, t=64 of the 128-tile (tt = wt*2+tts). Partial O / l
// combined once at the end via LDS (staging buffers reused; zero extra LDS).
// l is computed by a row-sum MFMA (ones x P) instead of 32 VALU adds/iter:
// every lane's lsum[0] = full sum over its t-range for q=lane&31.
// ---------------------------------------------------------------------------
__global__ __launch_bounds__(512, 4) void attn_kernel(
    const u16* __restrict__ qb, const u16* __restrict__ kb,
    const u16* __restrict__ vbT, u16* __restrict__ ctxb)
{
    __shared__ __align__(16) u16 kst[2][128 * 64];  // [t][d] chunks, swizzled
    __shared__ __align__(16) u16 vst[2][64 * 128];  // [e][t] chunks, swizzled

    const int tid  = threadIdx.x;
    const int lane = tid & 63, wid = tid >> 6;   // 8 waves
    const int wq = wid & 3, wt = wid >> 2;       // 4 q-waves x 2 t-halves
    const int l31  = lane & 31, hh = lane >> 5;
    const int bh = blockIdx.y;
    const int q0 = blockIdx.x * 128;
    const int b = bh >> 3, h = bh & 7;

    const u16* qg = qb + (size_t)bh * Sq * Eh;
    const u16* kg = kb + (size_t)bh * Sq * Eh;
    const u16* vg = vbT + (size_t)bh * Eh * Sq;

    // staging geometry: 1024 16B-chunks per tensor, 2 async16/lane/tensor.
    // K tile [t 0..127][d 0..63]: row=ci>>3, col=ci&7, XOR row&7.
    // V tile [e 0..63][t 0..127]: row=ci>>4, col=ci&15, XOR low-3 bits.
    int krow[2], kcol[2], vrow[2], vcol[2];
#pragma unroll
    for (int j = 0; j < 2; ++j) {
        int ci = wid * 128 + j * 64 + lane;
        krow[j] = ci >> 3;
        kcol[j] = (ci & 7) ^ (krow[j] & 7);
        vrow[j] = ci >> 4;
        int vc  = ci & 15;
        vcol[j] = (vc & 8) | ((vc & 7) ^ (vrow[j] & 7));
    }

    // Q B-frags (n=q=lane&31, k=d=ks*16+hh*8+j) in registers for the kernel
    bf16x8 qf[4];
    {
        const u16* qrow = &qg[(size_t)(q0 + wq * 32 + l31) * Eh + hh * 8];
#pragma unroll
        for (int ks = 0; ks < 4; ++ks)
            qf[ks] = *(const bf16x8*)&qrow[ks * 16];
    }

    // ones A-frag for the row-sum MFMA (bf16 1.0 = 0x3F80)
    bf16x8 ones;
    {
        union { unsigned u[4]; bf16x8 v; } t;
        t.u[0] = t.u[1] = t.u[2] = t.u[3] = 0x3F803F80u;
        ones = t.v;
    }

    f32x16 O[2], lsum;           // O^T[e-tile]; lsum rows all = sum_t P[t][q]
    O[0] = (f32x16)0.0f;
    O[1] = (f32x16)0.0f;
    lsum = (f32x16)0.0f;

    // issue tile 0 into buffer 0
#pragma unroll
    for (int j = 0; j < 2; ++j) {
        async16(&kg[(size_t)krow[j] * Eh + kcol[j] * 8],
                &kst[0][(wid * 128 + j * 64) * 8]);
        async16(&vg[(size_t)vrow[j] * Sq + vcol[j] * 8],
                &vst[0][(wid * 128 + j * 64) * 8]);
    }

    const int t7 = l31 & 7;      // (tt*32+l31)&7 == (et*32+l31)&7

    for (int kt = 0; kt < Sq / 128; ++kt) {
        const int cur = kt & 1;
        __syncthreads();   // drains tile kt's async loads; frees other buffer

        if (kt < Sq / 128 - 1) {
            const int t1 = (kt + 1) * 128;
#pragma unroll
            for (int j = 0; j < 2; ++j) {
                async16(&kg[(size_t)(t1 + krow[j]) * Eh + kcol[j] * 8],
                        &kst[cur ^ 1][(wid * 128 + j * 64) * 8]);
                async16(&vg[(size_t)vrow[j] * Sq + t1 + vcol[j] * 8],
                        &vst[cur ^ 1][(wid * 128 + j * 64) * 8]);
            }
        }

        const u16* kcur = kst[cur];
        const u16* vcur = vst[cur];

#pragma unroll
        for (int tts = 0; tts < 2; ++tts) {
            const int tt = wt * 2 + tts;   // this wave's 32-t subtile
            // ---- S^T(32t x 32q) = K' Q^T, 4x 32x32x16 over d ----
            f32x16 S = (f32x16)0.0f;
            const int trow = (tt * 32 + l31) * 64;
#pragma unroll
            for (int ks = 0; ks < 4; ++ks) {
                bf16x8 kf = *(const bf16x8*)&kcur[trow + ((ks * 2 + hh) ^ t7) * 8];
                S = mfma_32x32x16(kf, qf[ks], S);
            }

            // ---- exp2 + pack pairs + permlane32_swap -> PV B-frags ----
            unsigned px[8];
#pragma unroll
            for (int j = 0; j < 8; ++j) {
                float p0 = fast_exp2(S[2 * j]);
                float p1 = fast_exp2(S[2 * j + 1]);
                px[j] = cvt_pk_bf16(p0, p1);
            }
            plane32_swap(px[0], px[2]);
            plane32_swap(px[1], px[3]);
            plane32_swap(px[4], px[6]);
            plane32_swap(px[5], px[7]);
            bf16x8 f0 = frag_of(px[0], px[1], px[2], px[3]);  // t 0..15 of tile
            bf16x8 f1 = frag_of(px[4], px[5], px[6], px[7]);  // t 16..31

            // ---- l row-sum on the matrix pipe ----
            lsum = mfma_32x32x16(ones, f0, lsum);
            lsum = mfma_32x32x16(ones, f1, lsum);

            // ---- O^T += V^T P^T (A = V^T: m=e, k=t) ----
#pragma unroll
            for (int et = 0; et < 2; ++et) {
                const int erow = (et * 32 + l31) * 128;
                int c0 = tt * 4 + hh;         // 16B chunk for kb = 2tt
                int c1 = c0 + 2;              // kb = 2tt+1
                int g0 = (c0 & 8) | ((c0 & 7) ^ t7);
                int g1 = (c1 & 8) | ((c1 & 7) ^ t7);
                bf16x8 v0 = *(const bf16x8*)&vcur[erow + g0 * 8];
                bf16x8 v1 = *(const bf16x8*)&vcur[erow + g1 * 8];
                O[et] = mfma_32x32x16(v0, f0, O[et]);
                O[et] = mfma_32x32x16(v1, f1, O[et]);
            }
        }
    }

    // ---- cross-(wt) reduction via LDS (staging buffers reused) ----
    __syncthreads();                          // all tile compute done
    float* redO = (float*)&kst[0][0];         // 8192 floats = 4 wq x 64 x 32
    float* redL = (float*)&vst[0][0];
    const int rbase = (wq * 64 + lane) * 32;
    if (wt == 1) {
#pragma unroll
        for (int et = 0; et < 2; ++et)
#pragma unroll
            for (int c = 0; c < 4; ++c) {
                f32x4 v4;
#pragma unroll
                for (int i = 0; i < 4; ++i) v4[i] = O[et][c * 4 + i];
                // XOR-swizzled 16B chunk slot (writer/reader use same map)
                *(f32x4*)&redO[rbase + (((et * 4 + c) ^ (lane & 7)) * 4)] = v4;
            }
        redL[wq * 64 + lane] = lsum[0];
    }
    __syncthreads();
    if (wt == 0) {
#pragma unroll
        for (int et = 0; et < 2; ++et)
#pragma unroll
            for (int c = 0; c < 4; ++c) {
                f32x4 v4 = *(const f32x4*)&redO[rbase + (((et * 4 + c) ^ (lane & 7)) * 4)];
#pragma unroll
                for (int i = 0; i < 4; ++i) O[et][c * 4 + i] += v4[i];
            }
        const float lp = lsum[0] + redL[wq * 64 + lane];
        const float rl = 1.0f / lp;

        // ---- normalize (per-lane q = l31) and store u16x4 along e ----
        const int qglob = q0 + wq * 32 + l31;
        u16* crow = ctxb + ((size_t)(b * Sq + qglob) * Hn + h) * Eh;
#pragma unroll
        for (int et = 0; et < 2; ++et)
#pragma unroll
            for (int g = 0; g < 4; ++g) {
                u16x4 o;
#pragma unroll
                for (int i = 0; i < 4; ++i) o[i] = f2bf(O[et][g * 4 + i] * rl);
                *(u16x4*)&crow[et * 32 + g * 8 + hh * 4] = o;
            }
    }
}

// ---------------------------------------------------------------------------
// Flat GEMM [8192,512] x WT[512,512], tile 128x64 (512 blocks, 2/CU).
// MODE 0: bf16 out; 1: bf16 out + relu; 2: fp32 out.
// ---------------------------------------------------------------------------
template<int MODE>
__global__ __launch_bounds__(256, 2) void gemmMN(
    const u16* __restrict__ A, const u16* __restrict__ WT,
    const float* __restrict__ bias, void* __restrict__ Cout)
{
    __shared__ __align__(16) u16 Ast[128 * 64];
    __shared__ __align__(16) u16 Bst[64 * 64];

    f32x4 acc[4][2];
#pragma unroll
    for (int i = 0; i < 4; ++i)
#pragma unroll
        for (int j = 0; j < 2; ++j) acc[i][j] = (f32x4)0.0f;

    gemm_core<64, 2>(A, WT, blockIdx.x * 128, blockIdx.y * 64, Ast, Bst, acc);

    const int tid = threadIdx.x;
    const int lane = tid & 63, wid = tid >> 6;
    const int l15 = lane & 15, quad = lane >> 4;
    const int m0 = blockIdx.x * 128 + (wid >> 1) * 64;
    const int n0 = blockIdx.y * 64 + (wid & 1) * 32;

#pragma unroll
    for (int mt = 0; mt < 4; ++mt)
#pragma unroll
        for (int nt = 0; nt < 2; ++nt) {
            int col = n0 + nt * 16 + l15;
            float bval = bias[col];
#pragma unroll
            for (int r = 0; r < 4; ++r) {
                int row = m0 + mt * 16 + quad * 4 + r;
                float v = acc[mt][nt][r] + bval;
                if (MODE == 1) v = fmaxf(v, 0.0f);
                if (MODE == 2) ((float*)Cout)[(size_t)row * Dm + col] = v;
                else           ((u16*)Cout)[(size_t)row * Dm + col] = f2bf(v);
            }
        }
}

extern "C" void kernel_launch(void* const* d_in, const int* in_sizes, int n_in,
                              void* d_out, int out_size, void* d_ws, size_t ws_size,
                              hipStream_t stream)
{
    const float* x  = (const float*)d_in[0];
    const float* wq = (const float*)d_in[1];
    const float* bq = (const float*)d_in[2];
    const float* wk = (const float*)d_in[3];
    const float* bk = (const float*)d_in[4];
    const float* wv = (const float*)d_in[5];
    const float* bv = (const float*)d_in[6];
    const float* wo = (const float*)d_in[7];
    const float* bo = (const float*)d_in[8];
    const float* w1 = (const float*)d_in[9];
    const float* b1 = (const float*)d_in[10];
    const float* w2 = (const float*)d_in[11];
    const float* b2 = (const float*)d_in[12];
    float* out = (float*)d_out;
    char* wsb = (char*)d_ws;

    const size_t MB = 1u << 20;
    u16*   xb    = (u16*)(wsb + 0);        // 8 MB  bf16 [B*S, D]
    u16*   qb    = (u16*)(wsb + 8 * MB);   // 8 MB  [bh][s][e]
    u16*   kb    = (u16*)(wsb + 16 * MB);  // 8 MB  [bh][s][e] (pre-scaled)
    u16*   vbT   = (u16*)(wsb + 24 * MB);  // 8 MB  [bh][e][s]
    u16*   ctxb  = (u16*)(wsb + 32 * MB);  // 8 MB  [b][s][h][e]
    u16*   ybuf  = (u16*)(wsb + 40 * MB);  // 8 MB
    u16*   h1    = (u16*)(wsb + 48 * MB);  // 8 MB
    u16*   wqkvT = (u16*)(wsb + 56 * MB);  // 1.5 MB
    u16*   woT   = (u16*)(wsb + 58 * MB);  // 0.5 MB
    u16*   w1T   = (u16*)(wsb + 59 * MB);  // 0.5 MB
    u16*   w2T   = (u16*)(wsb + 60 * MB);  // 0.5 MB
    float* bo_s  = (float*)(wsb + 61 * MB);

    prep_kernel<<<dim3(64, 8), 256, 0, stream>>>(
        x, wq, wk, wv, wo, w1, w2, bo, xb, wqkvT, woT, w1T, w2T, bo_s);
    qkv_gemm<<<dim3(Sq * Bsz / 128, 24), 256, 0, stream>>>(
        xb, wqkvT, bq, bk, bv, qb, kb, vbT);
    attn_kernel<<<dim3(Sq / 128, Bsz * Hn), 512, 0, stream>>>(qb, kb, vbT, ctxb);
    gemmMN<0><<<dim3(Bsz * Sq / 128, Dm / 64), 256, 0, stream>>>(ctxb, woT, bo_s, ybuf);
    gemmMN<1><<<dim3(Bsz * Sq / 128, Dm / 64), 256, 0, stream>>>(ybuf, w1T, b1, h1);
    gemmMN<2><<<dim3(Bsz * Sq / 128, Dm / 64), 256, 0, stream>>>(h1, w2T, b2, out);
}

// Round 5
// 223.756 us; speedup vs baseline: 1.0937x; 1.0550x over previous
//
#include <hip/hip_runtime.h>
#include <math.h>

#define Bsz 2
#define Sq  4096
#define Dm  512
#define Hn  8
#define Eh  64

typedef unsigned short u16;
typedef __attribute__((ext_vector_type(8))) short bf16x8;   // 8 bf16 in 4 VGPRs
typedef __attribute__((ext_vector_type(4))) float f32x4;
typedef __attribute__((ext_vector_type(16))) float f32x16;
typedef __attribute__((ext_vector_type(4))) unsigned short u16x4;

// K pre-scale: 1/sqrt(64) * log2(e), folded into k so softmax is a bare exp2.
#define KSCALE 0.18033688011112042f

__device__ __forceinline__ u16 f2bf(float f) {
    unsigned int u = __float_as_uint(f);
    u += 0x7FFFu + ((u >> 16) & 1u);          // round-to-nearest-even
    return (u16)(u >> 16);
}

__device__ __forceinline__ float fast_exp2(float x) {
#if defined(__HIP_DEVICE_COMPILE__) && __has_builtin(__builtin_amdgcn_exp2f)
    return __builtin_amdgcn_exp2f(x);
#else
    return exp2f(x);
#endif
}

// 32x32x16 bf16 MFMA. A: m=lane&31, k=(lane>>5)*8+j. B: n=lane&31, same k.
// D: col=lane&31, row=(r&3)+8*(r>>2)+4*(lane>>5)  [m74/m101-verified].
__device__ __forceinline__ f32x16 mfma_32x32x16(bf16x8 a, bf16x8 b, f32x16 c) {
#if defined(__HIP_DEVICE_COMPILE__)
    return __builtin_amdgcn_mfma_f32_32x32x16_bf16(a, b, c, 0, 0, 0);
#else
    (void)a; (void)b;
    return c;
#endif
}

// v_cvt_pk_bf16_f32: u32 = {hi: bf16(hi), lo: bf16(lo)}  (no builtin on gfx950)
__device__ __forceinline__ unsigned cvt_pk_bf16(float lo, float hi) {
#if defined(__HIP_DEVICE_COMPILE__)
    unsigned r;
    asm("v_cvt_pk_bf16_f32 %0, %1, %2" : "=v"(r) : "v"(lo), "v"(hi));
    return r;
#else
    return ((unsigned)f2bf(hi) << 16) | (unsigned)f2bf(lo);
#endif
}

// v_permlane32_swap_b32: a' = [a.lanes0-31, b.lanes0-31], b' = [a.lanes32-63, b.lanes32-63]
__device__ __forceinline__ void plane32_swap(unsigned &a, unsigned &b) {
#if defined(__HIP_DEVICE_COMPILE__)
    asm volatile("v_permlane32_swap_b32 %0, %1" : "+v"(a), "+v"(b));
#endif
}

__device__ __forceinline__ bf16x8 frag_of(unsigned a, unsigned b, unsigned c, unsigned d) {
    union { unsigned u[4]; bf16x8 v; } r;
    r.u[0] = a; r.u[1] = b; r.u[2] = c; r.u[3] = d;
    return r.v;
}

// async global->LDS, 16B per lane. LDS dest = wave-uniform base + lane*16.
__device__ __forceinline__ void async16(const u16* g, u16* l) {
    __builtin_amdgcn_global_load_lds(
        (const __attribute__((address_space(1))) void*)g,
        (__attribute__((address_space(3))) void*)l, 16, 0, 0);
}

// ---------------------------------------------------------------------------
// bf16 MFMA GEMM core (R2-passing single-buffered version; the counted-vmcnt
// rewrite failed correctness twice with an unlocalizable race — reverted).
// C[128 x TN] += A[128,512] * WT[TN,512]^T, K=Dm=512.
// Global-side XOR chunk swizzle; 4 waves as 2(M)x2(N).
// ---------------------------------------------------------------------------
template<int TN, int NT>
__device__ __forceinline__ void gemm_core(
    const u16* __restrict__ A, const u16* __restrict__ WT,
    int m0, int n0, u16* Ast, u16* Bst, f32x4 (&acc)[4][NT])
{
    const int tid  = threadIdx.x;
    const int lane = tid & 63, wid = tid >> 6;
    const int l15  = lane & 15, quad = lane >> 4;
    const int wm = wid >> 1, wn = wid & 1;

    for (int kt = 0; kt < Dm / 64; ++kt) {
        const int k0 = kt * 64;
        __syncthreads();
#pragma unroll
        for (int j = 0; j < 4; ++j) {
            int ci = wid * 256 + j * 64 + lane;
            int row = ci >> 3, c = (ci & 7) ^ (row & 7);
            async16(&A[(size_t)(m0 + row) * Dm + k0 + c * 8],
                    &Ast[(size_t)(wid * 256 + j * 64) * 8]);
        }
#pragma unroll
        for (int j = 0; j < TN / 32; ++j) {
            int ci = wid * (TN * 2) + j * 64 + lane;
            int row = ci >> 3, c = (ci & 7) ^ (row & 7);
            async16(&WT[(size_t)(n0 + row) * Dm + k0 + c * 8],
                    &Bst[(size_t)(wid * (TN * 2) + j * 64) * 8]);
        }
        __syncthreads();
#pragma unroll
        for (int ks = 0; ks < 2; ++ks) {
            bf16x8 af[4], bfr[NT];
#pragma unroll
            for (int mt = 0; mt < 4; ++mt) {
                int r = wm * 64 + mt * 16 + l15;
                af[mt] = *(const bf16x8*)&Ast[(r * 8 + ((ks * 4 + quad) ^ (r & 7))) * 8];
            }
#pragma unroll
            for (int nt = 0; nt < NT; ++nt) {
                int n = wn * (TN / 2) + nt * 16 + l15;
                bfr[nt] = *(const bf16x8*)&Bst[(n * 8 + ((ks * 4 + quad) ^ (n & 7))) * 8];
            }
#pragma unroll
            for (int mt = 0; mt < 4; ++mt)
#pragma unroll
                for (int nt = 0; nt < NT; ++nt)
                    acc[mt][nt] = __builtin_amdgcn_mfma_f32_16x16x32_bf16(
                        af[mt], bfr[nt], acc[mt][nt], 0, 0, 0);
        }
    }
}

// ---------------------------------------------------------------------------
// prep: seg0 x->bf16 (spread over all 128 x-blocks); seg1-3 wq/wk/wv
// transpose; seg4-6 wo/w1/w2 transpose; seg7 bo reduce (segs 1-6 use bx<64).
// ---------------------------------------------------------------------------
__global__ __launch_bounds__(256) void prep_kernel(
    const float* __restrict__ x,
    const float* __restrict__ wq, const float* __restrict__ wk,
    const float* __restrict__ wv, const float* __restrict__ wo,
    const float* __restrict__ w1, const float* __restrict__ w2,
    const float* __restrict__ bo,
    u16* __restrict__ xb, u16* __restrict__ wqkvT, u16* __restrict__ woT,
    u16* __restrict__ w1T, u16* __restrict__ w2T, float* __restrict__ bo_s)
{
    const int seg = blockIdx.y, bx = blockIdx.x, tid = threadIdx.x;
    if (seg == 0) {
        const float4* xi = (const float4*)x;
        const int stride = gridDim.x * 256;
        for (int i = bx * 256 + tid; i < (Bsz * Sq * Dm) / 4; i += stride) {
            float4 v = xi[i];
            u16x4 o = {f2bf(v.x), f2bf(v.y), f2bf(v.z), f2bf(v.w)};
            *(u16x4*)&xb[(size_t)i * 4] = o;
        }
        return;
    }
    if (seg == 7) {
        int d = bx * 256 + tid;
        if (d < Dm) {
            float s = 0.0f;
#pragma unroll
            for (int h = 0; h < Hn; ++h) s += bo[h * Dm + d];
            bo_s[d] = s;
        }
        return;
    }
    if (bx >= 64) return;
    __shared__ float t[64][65];
    const float* src; u16* dst; int ld_in;
    if (seg <= 3) {
        const float* w = (seg == 1) ? wq : (seg == 2) ? wk : wv;
        int head = bx >> 3, kt = bx & 7;
        src = w + (size_t)head * Dm * Eh + (size_t)kt * 64 * 64;
        ld_in = 64;
        dst = wqkvT + ((size_t)((seg - 1) * 8 + head) * 64) * 512 + kt * 64;
    } else {
        const float* w = (seg == 4) ? wo : (seg == 5) ? w1 : w2;
        u16* dT = (seg == 4) ? woT : (seg == 5) ? w1T : w2T;
        int tr = bx >> 3, tc = bx & 7;
        src = w + (size_t)(tr * 64) * 512 + tc * 64;
        ld_in = 512;
        dst = dT + (size_t)(tc * 64) * 512 + tr * 64;
    }
#pragma unroll
    for (int it = 0; it < 16; ++it) {
        int idx = it * 256 + tid;
        int r = idx >> 6, c = idx & 63;
        t[r][c] = src[(size_t)r * ld_in + c];
    }
    __syncthreads();
#pragma unroll
    for (int it = 0; it < 4; ++it) {
        int idx = it * 256 + tid;
        int oc = idx >> 4, og = idx & 15;
        u16x4 o;
#pragma unroll
        for (int j = 0; j < 4; ++j) o[j] = f2bf(t[og * 4 + j][oc]);
        *(u16x4*)&dst[(size_t)oc * 512 + og * 4] = o;
    }
}

// ---------------------------------------------------------------------------
// QKV: grid (64, 24). Tile 128x64. q -> [bh][s][e]; k -> [bh][s][e] scaled
// by KSCALE (folded softmax scale + log2e); v -> transposed [bh][e][s].
// ---------------------------------------------------------------------------
__global__ __launch_bounds__(256, 2) void qkv_gemm(
    const u16* __restrict__ xb, const u16* __restrict__ wqkvT,
    const float* __restrict__ bq, const float* __restrict__ bk,
    const float* __restrict__ bv,
    u16* __restrict__ qb, u16* __restrict__ kb, u16* __restrict__ vbT)
{
    __shared__ __align__(16) u16 Ast[128 * 64];
    __shared__ __align__(16) u16 Bst[64 * 64];
    const int proj = blockIdx.y >> 3, h = blockIdx.y & 7;
    const u16* WT = wqkvT + (size_t)blockIdx.y * 64 * 512;

    f32x4 acc[4][2];
#pragma unroll
    for (int i = 0; i < 4; ++i)
#pragma unroll
        for (int j = 0; j < 2; ++j) acc[i][j] = (f32x4)0.0f;

    gemm_core<64, 2>(xb, WT, blockIdx.x * 128, 0, Ast, Bst, acc);

    const int tid = threadIdx.x;
    const int lane = tid & 63, wid = tid >> 6;
    const int l15 = lane & 15, quad = lane >> 4;
    const int wm = wid >> 1, wn = wid & 1;
    const float* bias = (proj == 0) ? bq : (proj == 1) ? bk : bv;

    const int mbase = blockIdx.x * 128 + wm * 64;
    const int b = mbase >> 12;
    const int sbase = (mbase & (Sq - 1));
    const int bh = b * Hn + h;

#pragma unroll
    for (int mt = 0; mt < 4; ++mt)
#pragma unroll
        for (int nt = 0; nt < 2; ++nt) {
            int e = wn * 32 + nt * 16 + l15;
            float bval = bias[h * Eh + e];
            int s = sbase + mt * 16 + quad * 4;
            if (proj == 2) {
                u16x4 o;
#pragma unroll
                for (int r = 0; r < 4; ++r) o[r] = f2bf(acc[mt][nt][r] + bval);
                *(u16x4*)&vbT[((size_t)bh * Eh + e) * Sq + s] = o;
            } else if (proj == 1) {
                for (int r = 0; r < 4; ++r)
                    kb[((size_t)bh * Sq + s + r) * Eh + e] =
                        f2bf((acc[mt][nt][r] + bval) * KSCALE);
            } else {
                for (int r = 0; r < 4; ++r)
                    qb[((size_t)bh * Sq + s + r) * Eh + e] = f2bf(acc[mt][nt][r] + bval);
            }
        }
}

// ---------------------------------------------------------------------------
// bf16 MFMA flash attention v17 = v14 sync (R2-passing: one __syncthreads per
// 128-t tile, issue-next-then-compute) + sync-neutral compute improvements:
// merged QK (8 back-to-back MFMA for both t-subtiles), sm0/PV0/sm1/PV1
// interleave (softmax VALU of subtile 1 issues while PV subtile 0 drains),
// s_setprio(1) around MFMA clusters (T5). The counted-vmcnt schedule (v15/
// v16) failed correctness twice with an unlocalizable LDS race — abandoned.
// R2 post-mortem note: MfmaUtil 43 + VALUBusy 40 with cross-wave overlap
// means ~80% combined issue; remaining lever is instruction mix, not sync.
// ---------------------------------------------------------------------------
__global__ __launch_bounds__(512, 4) void attn_kernel(
    const u16* __restrict__ qb, const u16* __restrict__ kb,
    const u16* __restrict__ vbT, u16* __restrict__ ctxb)
{
    __shared__ __align__(16) u16 kst[2][128 * 64];  // [t][d] chunks, swizzled
    __shared__ __align__(16) u16 vst[2][64 * 128];  // [e][t] chunks, swizzled

    const int tid  = threadIdx.x;
    const int lane = tid & 63, wid = tid >> 6;   // 8 waves
    const int wq = wid & 3, wt = wid >> 2;       // 4 q-waves x 2 t-halves
    const int l31  = lane & 31, hh = lane >> 5;
    const int bh = blockIdx.y;
    const int q0 = blockIdx.x * 128;
    const int b = bh >> 3, h = bh & 7;

    const u16* qg = qb + (size_t)bh * Sq * Eh;
    const u16* kg = kb + (size_t)bh * Sq * Eh;
    const u16* vg = vbT + (size_t)bh * Eh * Sq;

    // staging geometry: 1024 16B-chunks per tensor, 2 async16/lane/tensor.
    int krow[2], kcol[2], vrow[2], vcol[2];
#pragma unroll
    for (int j = 0; j < 2; ++j) {
        int ci = wid * 128 + j * 64 + lane;
        krow[j] = ci >> 3;
        kcol[j] = (ci & 7) ^ (krow[j] & 7);
        vrow[j] = ci >> 4;
        int vc  = ci & 15;
        vcol[j] = (vc & 8) | ((vc & 7) ^ (vrow[j] & 7));
    }

    // Q B-frags (n=q=lane&31, k=d=ks*16+hh*8+j) in registers for the kernel
    bf16x8 qf[4];
    {
        const u16* qrow = &qg[(size_t)(q0 + wq * 32 + l31) * Eh + hh * 8];
#pragma unroll
        for (int ks = 0; ks < 4; ++ks)
            qf[ks] = *(const bf16x8*)&qrow[ks * 16];
    }

    // ones A-frag for the row-sum MFMA (bf16 1.0 = 0x3F80)
    bf16x8 ones;
    {
        union { unsigned u[4]; bf16x8 v; } t;
        t.u[0] = t.u[1] = t.u[2] = t.u[3] = 0x3F803F80u;
        ones = t.v;
    }

    f32x16 O[2], lsum;           // O^T[e-tile]; lsum rows all = sum_t P[t][q]
    O[0] = (f32x16)0.0f;
    O[1] = (f32x16)0.0f;
    lsum = (f32x16)0.0f;

    const int t7 = l31 & 7;      // (tt*32+l31)&7 == (et*32+l31)&7
    const int tt0 = wt * 2, tt1 = tt0 + 1;
    const int trow0 = (tt0 * 32 + l31) * 64;
    const int trow1 = (tt1 * 32 + l31) * 64;

    auto issueT = [&](int kt, int buf) {   // 4 loads/wave (2 K + 2 V)
        const int t1 = kt * 128;
#pragma unroll
        for (int j = 0; j < 2; ++j) {
            async16(&kg[(size_t)(t1 + krow[j]) * Eh + kcol[j] * 8],
                    &kst[buf][(wid * 128 + j * 64) * 8]);
            async16(&vg[(size_t)vrow[j] * Sq + t1 + vcol[j] * 8],
                    &vst[buf][(wid * 128 + j * 64) * 8]);
        }
    };

    auto compute_tile = [&](int bu) {
        const u16* kcur = kst[bu];
        const u16* vcur = vst[bu];
        f32x16 S0 = (f32x16)0.0f, S1 = (f32x16)0.0f;

        __builtin_amdgcn_s_setprio(1);
#pragma unroll
        for (int ks = 0; ks < 4; ++ks) {
            bf16x8 kf = *(const bf16x8*)&kcur[trow0 + ((ks * 2 + hh) ^ t7) * 8];
            S0 = mfma_32x32x16(kf, qf[ks], S0);
        }
#pragma unroll
        for (int ks = 0; ks < 4; ++ks) {
            bf16x8 kf = *(const bf16x8*)&kcur[trow1 + ((ks * 2 + hh) ^ t7) * 8];
            S1 = mfma_32x32x16(kf, qf[ks], S1);
        }
        __builtin_amdgcn_s_setprio(0);

        // ---- softmax + pack sub0 ----
        unsigned pa[8];
#pragma unroll
        for (int j = 0; j < 8; ++j) {
            float p0 = fast_exp2(S0[2 * j]);
            float p1 = fast_exp2(S0[2 * j + 1]);
            pa[j] = cvt_pk_bf16(p0, p1);
        }
        plane32_swap(pa[0], pa[2]); plane32_swap(pa[1], pa[3]);
        plane32_swap(pa[4], pa[6]); plane32_swap(pa[5], pa[7]);
        bf16x8 f0a = frag_of(pa[0], pa[1], pa[2], pa[3]);  // t 0..15 of sub0
        bf16x8 f1a = frag_of(pa[4], pa[5], pa[6], pa[7]);  // t 16..31

        // ---- PV sub0 + lsum ----
        __builtin_amdgcn_s_setprio(1);
        lsum = mfma_32x32x16(ones, f0a, lsum);
        lsum = mfma_32x32x16(ones, f1a, lsum);
#pragma unroll
        for (int et = 0; et < 2; ++et) {
            const int erow = (et * 32 + l31) * 128;
            int c0 = tt0 * 4 + hh, c1 = c0 + 2;
            int g0 = (c0 & 8) | ((c0 & 7) ^ t7);
            int g1 = (c1 & 8) | ((c1 & 7) ^ t7);
            bf16x8 v0 = *(const bf16x8*)&vcur[erow + g0 * 8];
            bf16x8 v1 = *(const bf16x8*)&vcur[erow + g1 * 8];
            O[et] = mfma_32x32x16(v0, f0a, O[et]);
            O[et] = mfma_32x32x16(v1, f1a, O[et]);
        }
        __builtin_amdgcn_s_setprio(0);

        // ---- softmax + pack sub1 (VALU overlaps PV sub0 in flight) ----
        unsigned pb[8];
#pragma unroll
        for (int j = 0; j < 8; ++j) {
            float p0 = fast_exp2(S1[2 * j]);
            float p1 = fast_exp2(S1[2 * j + 1]);
            pb[j] = cvt_pk_bf16(p0, p1);
        }
        plane32_swap(pb[0], pb[2]); plane32_swap(pb[1], pb[3]);
        plane32_swap(pb[4], pb[6]); plane32_swap(pb[5], pb[7]);
        bf16x8 f0b = frag_of(pb[0], pb[1], pb[2], pb[3]);
        bf16x8 f1b = frag_of(pb[4], pb[5], pb[6], pb[7]);

        // ---- PV sub1 + lsum ----
        __builtin_amdgcn_s_setprio(1);
        lsum = mfma_32x32x16(ones, f0b, lsum);
        lsum = mfma_32x32x16(ones, f1b, lsum);
#pragma unroll
        for (int et = 0; et < 2; ++et) {
            const int erow = (et * 32 + l31) * 128;
            int c0 = tt1 * 4 + hh, c1 = c0 + 2;
            int g0 = (c0 & 8) | ((c0 & 7) ^ t7);
            int g1 = (c1 & 8) | ((c1 & 7) ^ t7);
            bf16x8 v0 = *(const bf16x8*)&vcur[erow + g0 * 8];
            bf16x8 v1 = *(const bf16x8*)&vcur[erow + g1 * 8];
            O[et] = mfma_32x32x16(v0, f0b, O[et]);
            O[et] = mfma_32x32x16(v1, f1b, O[et]);
        }
        __builtin_amdgcn_s_setprio(0);
    };

    // ---- v14 main loop: one __syncthreads per tile (proven sync) ----
    issueT(0, 0);
    for (int kt = 0; kt < Sq / 128; ++kt) {
        const int cur = kt & 1;
        __syncthreads();   // drains tile kt's async loads; frees other buffer
        if (kt < Sq / 128 - 1) issueT(kt + 1, cur ^ 1);
        compute_tile(cur);
    }

    // ---- cross-(wt) reduction via LDS (staging buffers reused) ----
    __syncthreads();                          // all tile compute done
    float* redO = (float*)&kst[0][0];         // 8192 floats = 4 wq x 64 x 32
    float* redL = (float*)&vst[0][0];
    const int rbase = (wq * 64 + lane) * 32;
    if (wt == 1) {
#pragma unroll
        for (int et = 0; et < 2; ++et)
#pragma unroll
            for (int c = 0; c < 4; ++c) {
                f32x4 v4;
#pragma unroll
                for (int i = 0; i < 4; ++i) v4[i] = O[et][c * 4 + i];
                // XOR-swizzled 16B chunk slot (writer/reader use same map)
                *(f32x4*)&redO[rbase + (((et * 4 + c) ^ (lane & 7)) * 4)] = v4;
            }
        redL[wq * 64 + lane] = lsum[0];
    }
    __syncthreads();
    if (wt == 0) {
#pragma unroll
        for (int et = 0; et < 2; ++et)
#pragma unroll
            for (int c = 0; c < 4; ++c) {
                f32x4 v4 = *(const f32x4*)&redO[rbase + (((et * 4 + c) ^ (lane & 7)) * 4)];
#pragma unroll
                for (int i = 0; i < 4; ++i) O[et][c * 4 + i] += v4[i];
            }
        const float lp = lsum[0] + redL[wq * 64 + lane];
        const float rl = 1.0f / lp;

        // ---- normalize (per-lane q = l31) and store u16x4 along e ----
        const int qglob = q0 + wq * 32 + l31;
        u16* crow = ctxb + ((size_t)(b * Sq + qglob) * Hn + h) * Eh;
#pragma unroll
        for (int et = 0; et < 2; ++et)
#pragma unroll
            for (int g = 0; g < 4; ++g) {
                u16x4 o;
#pragma unroll
                for (int i = 0; i < 4; ++i) o[i] = f2bf(O[et][g * 4 + i] * rl);
                *(u16x4*)&crow[et * 32 + g * 8 + hh * 4] = o;
            }
    }
}

// ---------------------------------------------------------------------------
// Flat GEMM [8192,512] x WT[512,512], tile 128x64 (512 blocks, 2/CU).
// MODE 0: bf16 out; 1: bf16 out + relu; 2: fp32 out.
// ---------------------------------------------------------------------------
template<int MODE>
__global__ __launch_bounds__(256, 2) void gemmMN(
    const u16* __restrict__ A, const u16* __restrict__ WT,
    const float* __restrict__ bias, void* __restrict__ Cout)
{
    __shared__ __align__(16) u16 Ast[128 * 64];
    __shared__ __align__(16) u16 Bst[64 * 64];

    f32x4 acc[4][2];
#pragma unroll
    for (int i = 0; i < 4; ++i)
#pragma unroll
        for (int j = 0; j < 2; ++j) acc[i][j] = (f32x4)0.0f;

    gemm_core<64, 2>(A, WT, blockIdx.x * 128, blockIdx.y * 64, Ast, Bst, acc);

    const int tid = threadIdx.x;
    const int lane = tid & 63, wid = tid >> 6;
    const int l15 = lane & 15, quad = lane >> 4;
    const int m0 = blockIdx.x * 128 + (wid >> 1) * 64;
    const int n0 = blockIdx.y * 64 + (wid & 1) * 32;

#pragma unroll
    for (int mt = 0; mt < 4; ++mt)
#pragma unroll
        for (int nt = 0; nt < 2; ++nt) {
            int col = n0 + nt * 16 + l15;
            float bval = bias[col];
#pragma unroll
            for (int r = 0; r < 4; ++r) {
                int row = m0 + mt * 16 + quad * 4 + r;
                float v = acc[mt][nt][r] + bval;
                if (MODE == 1) v = fmaxf(v, 0.0f);
                if (MODE == 2) ((float*)Cout)[(size_t)row * Dm + col] = v;
                else           ((u16*)Cout)[(size_t)row * Dm + col] = f2bf(v);
            }
        }
}

extern "C" void kernel_launch(void* const* d_in, const int* in_sizes, int n_in,
                              void* d_out, int out_size, void* d_ws, size_t ws_size,
                              hipStream_t stream)
{
    const float* x  = (const float*)d_in[0];
    const float* wq = (const float*)d_in[1];
    const float* bq = (const float*)d_in[2];
    const float* wk = (const float*)d_in[3];
    const float* bk = (const float*)d_in[4];
    const float* wv = (const float*)d_in[5];
    const float* bv = (const float*)d_in[6];
    const float* wo = (const float*)d_in[7];
    const float* bo = (const float*)d_in[8];
    const float* w1 = (const float*)d_in[9];
    const float* b1 = (const float*)d_in[10];
    const float* w2 = (const float*)d_in[11];
    const float* b2 = (const float*)d_in[12];
    float* out = (float*)d_out;
    char* wsb = (char*)d_ws;

    const size_t MB = 1u << 20;
    u16*   xb    = (u16*)(wsb + 0);        // 8 MB  bf16 [B*S, D]
    u16*   qb    = (u16*)(wsb + 8 * MB);   // 8 MB  [bh][s][e]
    u16*   kb    = (u16*)(wsb + 16 * MB);  // 8 MB  [bh][s][e] (pre-scaled)
    u16*   vbT   = (u16*)(wsb + 24 * MB);  // 8 MB  [bh][e][s]
    u16*   ctxb  = (u16*)(wsb + 32 * MB);  // 8 MB  [b][s][h][e]
    u16*   ybuf  = (u16*)(wsb + 40 * MB);  // 8 MB
    u16*   h1    = (u16*)(wsb + 48 * MB);  // 8 MB
    u16*   wqkvT = (u16*)(wsb + 56 * MB);  // 1.5 MB
    u16*   woT   = (u16*)(wsb + 58 * MB);  // 0.5 MB
    u16*   w1T   = (u16*)(wsb + 59 * MB);  // 0.5 MB
    u16*   w2T   = (u16*)(wsb + 60 * MB);  // 0.5 MB
    float* bo_s  = (float*)(wsb + 61 * MB);

    prep_kernel<<<dim3(128, 8), 256, 0, stream>>>(
        x, wq, wk, wv, wo, w1, w2, bo, xb, wqkvT, woT, w1T, w2T, bo_s);
    qkv_gemm<<<dim3(Sq * Bsz / 128, 24), 256, 0, stream>>>(
        xb, wqkvT, bq, bk, bv, qb, kb, vbT);
    attn_kernel<<<dim3(Sq / 128, Bsz * Hn), 512, 0, stream>>>(qb, kb, vbT, ctxb);
    gemmMN<0><<<dim3(Bsz * Sq / 128, Dm / 64), 256, 0, stream>>>(ctxb, woT, bo_s, ybuf);
    gemmMN<1><<<dim3(Bsz * Sq / 128, Dm / 64), 256, 0, stream>>>(ybuf, w1T, b1, h1);
    gemmMN<2><<<dim3(Bsz * Sq / 128, Dm / 64), 256, 0, stream>>>(h1, w2T, b2, out);
}